// Round 5
// baseline (768.411 us; speedup 1.0000x reference)
//
#include <hip/hip_runtime.h>

#define TT 128
#define BB 32
#define II 128
#define HH 320
#define OO 32
#define GG 8
#define HPAD 129   // s_hist row pitch (pad: rows are read down-column in poll phase)

static __device__ __forceinline__ float fexp2(float x) { return __builtin_amdgcn_exp2f(x); }
static __device__ __forceinline__ float frcp(float x)  { return __builtin_amdgcn_rcpf(x); }

// tanh for x >= 0: 1 - 2/(e^{2x}+1), e^{2x} = exp2(x * 2*log2(e))
static __device__ __forceinline__ float tanh_pos(float x) {
    float e = fexp2(x * 2.8853900817779268f);
    return 1.0f - 2.0f * frcp(e + 1.0f);
}

// Two batches per block, staggered: hide batch-A's publish->detect round trip
// under batch-B's compute and vice versa. Per-batch arithmetic is bit-identical
// to the proven round-2 kernel (435us): same chains, same butterfly orders.
__global__ __launch_bounds__(512, 2)
void leaky_rnn_kernel(const float* __restrict__ x, const float* __restrict__ Rs,
                      const float* __restrict__ Wx2h, const float* __restrict__ Wh2h,
                      const float* __restrict__ bh2h, const float* __restrict__ Wh2o,
                      const float* __restrict__ bh2o, const float* __restrict__ Wattn,
                      const float* __restrict__ battn, const float* __restrict__ cplas,
                      float* __restrict__ out, float* __restrict__ hs,
                      unsigned* __restrict__ ctr)
{
    const int tid  = threadIdx.x;
    const int bid  = blockIdx.x;          // 128 blocks
    const int pair = bid >> 3;            // batch pair 0..15
    const int sub  = bid & 7;             // 8 sibling blocks per pair (spread over XCDs)
    const int bA   = pair * 2;
    const int bB   = bA + 1;
    const int w    = tid >> 6;            // wave 0..7
    const int lane = tid & 63;
    const int h0   = sub * 40;

    __shared__ float s_ea[GG * HH];       // masked relu(W_attn)  (shared by both batches)
    __shared__ float s_outA[HH];          // prev output, batch A
    __shared__ float s_outB[HH];          // prev output, batch B
    __shared__ float s_logit[2][GG];      // [0]=A, [1]=B
    __shared__ float s_histA[40 * HPAD];  // own 40 rows x 128 t, batch A (true values)
    __shared__ float s_histB[40 * HPAD];  // own 40 rows x 128 t, batch B
    __shared__ float s_hs[16 * HH];       // readout staging (reused A then B)

    // ---- one-time init ----
    for (int idx = tid; idx < GG * HH; idx += 512) {
        int h = idx % HH;
        float m = (h < 256) ? 1.f : (h == 256 ? -1.f : 0.f);  // mask_a (zc=63!)
        s_ea[idx] = fmaxf(Wattn[idx], 0.f) * m;
    }
    if (tid < HH) { s_outA[tid] = 0.f; s_outB[tid] = 0.f; }   // output0 = relu(0)

    // plastic weights in registers: 5 rows/wave, lane owns cols {lane, lane+64,...}
    // two full sets (batch A and batch B); static init identical for both.
    float wxA[5][2], whA[5][5], stA[5];
    float wxB[5][2], whB[5][5], stB[5];
    float bh[5];
    int hrow[5];
#pragma unroll
    for (int r = 0; r < 5; ++r) {
        int h = h0 + w * 5 + r;
        hrow[r] = h;
        bh[r] = bh2h[h];
        stA[r] = 0.f; stB[r] = 0.f;
#pragma unroll
        for (int c = 0; c < 2; ++c) {
            float v = fmaxf(Wx2h[h * II + lane + 64 * c], 0.f);   // wx0 = relu(W_x2h)
            wxA[r][c] = v; wxB[r][c] = v;
        }
#pragma unroll
        for (int c = 0; c < 5; ++c) {
            int j = lane + 64 * c;
            float v = fmaxf(Wh2h[h * HH + j], 0.f);
            v = (c == 4) ? -v : v;            // sign_h: j>=256 -> -1
            v = (j == h) ? 0.f : v;           // zero diagonal (1-eye)
            whA[r][c] = v; whB[r][c] = v;
        }
    }
    float batt = battn[w];  // wave w handles attn group g = w
    float c0 = fabsf(cplas[0]), c1 = fabsf(cplas[1]), c2 = fabsf(cplas[2]);
    float c3 = fabsf(cplas[3]), c4 = fabsf(cplas[4]), c5 = fabsf(cplas[5]);

    const float AX  = (float)(0.02 / 0.1);   // 0.2
    const float AW  = (float)(0.02 / 0.2);   // 0.1
    const float OMX = 1.f - AX;
    const float OMW = 1.f - AW;
    const float L2E = 1.4426950408889634f;

    __syncthreads();

    // prefetch x (both halves, both batches) and Rs for t=0
    float xA0n = x[bA * II + lane];
    float xA1n = x[bA * II + lane + 64];
    float xB0n = x[bB * II + lane];
    float xB1n = x[bB * II + lane + 64];
    float RvAn = Rs[bA];
    float RvBn = Rs[bB];

#pragma unroll 1
    for (int t = 0; t < TT; ++t) {
        const float AA = AW * RvAn;   // t-loop scope (used after B1a)
        const float AB = AW * RvBn;

        // ================= batch A step t =================
        {
            // ---- logits: wave w -> group w ----
            float lp = 0.f;
#pragma unroll
            for (int k = 0; k < 5; ++k) {
                int hh2 = lane + 64 * k;
                lp = fmaf(s_ea[w * HH + hh2], s_outA[hh2], lp);
            }
#pragma unroll
            for (int m = 1; m < 64; m <<= 1) lp += __shfl_xor(lp, m, 64);
            if (lane == 0) s_logit[0][w] = lp + batt;
        }
        __syncthreads();                                  // B1a
        {
            // ---- per-thread softmax (round-2 op order) ----
            float lg[8];
#pragma unroll
            for (int g = 0; g < 8; ++g) lg[g] = s_logit[0][g];
            float mx = lg[0];
#pragma unroll
            for (int g = 1; g < 8; ++g) mx = fmaxf(mx, lg[g]);
            float se = 0.f, eg[8];
#pragma unroll
            for (int g = 0; g < 8; ++g) { eg[g] = fexp2((lg[g] - mx) * L2E); se += eg[g]; }
            float rinv = frcp(se);
            float xmc0 = xA0n * eg[lane >> 4] * 8.f * rinv;
            float xmc1 = xA1n * eg[(lane >> 4) + 4] * 8.f * rinv;

            float oc[5];
#pragma unroll
            for (int c = 0; c < 5; ++c) oc[c] = s_outA[lane + 64 * c];

            float p[5];
#pragma unroll
            for (int r = 0; r < 5; ++r) {
                int h = hrow[r];
                float pp = fmaxf(wxA[r][0], 0.f) * xmc0;
                pp = fmaf(fmaxf(wxA[r][1], 0.f), xmc1, pp);
#pragma unroll
                for (int c = 0; c < 5; ++c) {
                    float wv = fmaxf(whA[r][c], 0.f);
                    float so = (c == 4) ? -oc[4] : oc[c];
                    float term = wv * so;
                    term = ((lane + 64 * c) == h) ? 0.f : term;
                    pp += term;
                }
                p[r] = pp;
            }
#pragma unroll
            for (int m = 1; m < 64; m <<= 1) {
#pragma unroll
                for (int r = 0; r < 5; ++r) p[r] += __shfl_xor(p[r], m, 64);
            }

            float no[5];
#pragma unroll
            for (int r = 0; r < 5; ++r) {
                float total = p[r] + bh[r];
                stA[r] = fmaf(stA[r], OMX, total * AX);
                no[r] = tanh_pos(fmaxf(stA[r], 0.f));
            }

            // publish A rows (coalesced 5-lane line), biased +2
            float pub = no[0];
            pub = (lane == 1) ? no[1] : pub;
            pub = (lane == 2) ? no[2] : pub;
            pub = (lane == 3) ? no[3] : pub;
            pub = (lane == 4) ? no[4] : pub;
            if (lane < 5) {
                __hip_atomic_store(&hs[(t * BB + bA) * HH + h0 + w * 5 + lane], pub + 2.0f,
                                   __ATOMIC_RELAXED, __HIP_MEMORY_SCOPE_AGENT);
                s_histA[(w * 5 + lane) * HPAD + t] = pub;
            }

            // plastic update A
            if (t < TT - 1) {
                float Ac0 = AA * c0, Ac1 = AA * c1, Ac2 = AA * c2;
                float Ac3 = AA * c3, Ac4 = AA * c4, Ac5 = AA * c5;
#pragma unroll
                for (int r = 0; r < 5; ++r) {
                    float u  = fmaf(Ac2, no[r], Ac0);
                    float v  = Ac1 * no[r];
                    float pq = fmaf(Ac5, no[r], Ac3);
                    float qq = Ac4 * no[r];
                    wxA[r][0] = fmaf(wxA[r][0], OMW, fmaf(u, xmc0, v));
                    wxA[r][1] = fmaf(wxA[r][1], OMW, fmaf(u, xmc1, v));
#pragma unroll
                    for (int c = 0; c < 5; ++c)
                        whA[r][c] = fmaf(whA[r][c], OMW, fmaf(pq, oc[c], qq));
                }
            }
        }

        // ======== P_B: gather batch-B outputs of step t-1 (published half a
        //          period ago -> detect cheap). Own rows from LDS (safely
        //          ordered: >=2 barriers since the s_histB write). ========
        if (t > 0 && tid < HH) {
            float v;
            if (tid >= h0 && tid < h0 + 40) {
                v = s_histB[(tid - h0) * HPAD + (t - 1)];
            } else {
                const float* p2 = &hs[((t - 1) * BB + bB) * HH + tid];
                int guard = 0;
                do {
                    v = __hip_atomic_load(p2, __ATOMIC_RELAXED, __HIP_MEMORY_SCOPE_AGENT);
                    if (++guard > 2000000) break;
                } while (v < 1.0f);
                v -= 2.0f;
            }
            s_outB[tid] = v;
        }
        __syncthreads();                                  // B2b

        // ================= batch B step t =================
        {
            float lp = 0.f;
#pragma unroll
            for (int k = 0; k < 5; ++k) {
                int hh2 = lane + 64 * k;
                lp = fmaf(s_ea[w * HH + hh2], s_outB[hh2], lp);
            }
#pragma unroll
            for (int m = 1; m < 64; m <<= 1) lp += __shfl_xor(lp, m, 64);
            if (lane == 0) s_logit[1][w] = lp + batt;
        }
        __syncthreads();                                  // B1b
        {
            float lg[8];
#pragma unroll
            for (int g = 0; g < 8; ++g) lg[g] = s_logit[1][g];
            float mx = lg[0];
#pragma unroll
            for (int g = 1; g < 8; ++g) mx = fmaxf(mx, lg[g]);
            float se = 0.f, eg[8];
#pragma unroll
            for (int g = 0; g < 8; ++g) { eg[g] = fexp2((lg[g] - mx) * L2E); se += eg[g]; }
            float rinv = frcp(se);
            float xmc0 = xB0n * eg[lane >> 4] * 8.f * rinv;
            float xmc1 = xB1n * eg[(lane >> 4) + 4] * 8.f * rinv;

            float oc[5];
#pragma unroll
            for (int c = 0; c < 5; ++c) oc[c] = s_outB[lane + 64 * c];

            float p[5];
#pragma unroll
            for (int r = 0; r < 5; ++r) {
                int h = hrow[r];
                float pp = fmaxf(wxB[r][0], 0.f) * xmc0;
                pp = fmaf(fmaxf(wxB[r][1], 0.f), xmc1, pp);
#pragma unroll
                for (int c = 0; c < 5; ++c) {
                    float wv = fmaxf(whB[r][c], 0.f);
                    float so = (c == 4) ? -oc[4] : oc[c];
                    float term = wv * so;
                    term = ((lane + 64 * c) == h) ? 0.f : term;
                    pp += term;
                }
                p[r] = pp;
            }
#pragma unroll
            for (int m = 1; m < 64; m <<= 1) {
#pragma unroll
                for (int r = 0; r < 5; ++r) p[r] += __shfl_xor(p[r], m, 64);
            }

            float no[5];
#pragma unroll
            for (int r = 0; r < 5; ++r) {
                float total = p[r] + bh[r];
                stB[r] = fmaf(stB[r], OMX, total * AX);
                no[r] = tanh_pos(fmaxf(stB[r], 0.f));
            }

            float pub = no[0];
            pub = (lane == 1) ? no[1] : pub;
            pub = (lane == 2) ? no[2] : pub;
            pub = (lane == 3) ? no[3] : pub;
            pub = (lane == 4) ? no[4] : pub;
            if (lane < 5) {
                __hip_atomic_store(&hs[(t * BB + bB) * HH + h0 + w * 5 + lane], pub + 2.0f,
                                   __ATOMIC_RELAXED, __HIP_MEMORY_SCOPE_AGENT);
                s_histB[(w * 5 + lane) * HPAD + t] = pub;
            }

            if (t < TT - 1) {
                float Ac0 = AB * c0, Ac1 = AB * c1, Ac2 = AB * c2;
                float Ac3 = AB * c3, Ac4 = AB * c4, Ac5 = AB * c5;
#pragma unroll
                for (int r = 0; r < 5; ++r) {
                    float u  = fmaf(Ac2, no[r], Ac0);
                    float v  = Ac1 * no[r];
                    float pq = fmaf(Ac5, no[r], Ac3);
                    float qq = Ac4 * no[r];
                    wxB[r][0] = fmaf(wxB[r][0], OMW, fmaf(u, xmc0, v));
                    wxB[r][1] = fmaf(wxB[r][1], OMW, fmaf(u, xmc1, v));
#pragma unroll
                    for (int c = 0; c < 5; ++c)
                        whB[r][c] = fmaf(whB[r][c], OMW, fmaf(pq, oc[c], qq));
                }
            }
        }

        // prefetch next x/R for both batches while B's publishes are in flight
        if (t + 1 < TT) {
            xA0n = x[((t + 1) * BB + bA) * II + lane];
            xA1n = x[((t + 1) * BB + bA) * II + lane + 64];
            xB0n = x[((t + 1) * BB + bB) * II + lane];
            xB1n = x[((t + 1) * BB + bB) * II + lane + 64];
            RvAn = Rs[(t + 1) * BB + bA];
            RvBn = Rs[(t + 1) * BB + bB];
        }

        // ======== P_A: gather batch-A outputs of step t (published half a
        //          period ago, behind B's full compute). ========
        if (t < TT - 1 && tid < HH) {
            float v;
            if (tid >= h0 && tid < h0 + 40) {
                v = s_histA[(tid - h0) * HPAD + t];
            } else {
                const float* p2 = &hs[(t * BB + bA) * HH + tid];
                int guard = 0;
                do {
                    v = __hip_atomic_load(p2, __ATOMIC_RELAXED, __HIP_MEMORY_SCOPE_AGENT);
                    if (++guard > 2000000) break;
                } while (v < 1.0f);
                v -= 2.0f;
            }
            s_outA[tid] = v;
        }
        __syncthreads();                                  // B2a
    }

    // ======== final phase ========
    // Barrier A among the 8 sibling blocks, for BOTH batches.
    if (tid == 0) {
        __hip_atomic_fetch_add(&ctr[bA * 32], 1u, __ATOMIC_RELAXED, __HIP_MEMORY_SCOPE_AGENT);
        __hip_atomic_fetch_add(&ctr[bB * 32], 1u, __ATOMIC_RELAXED, __HIP_MEMORY_SCOPE_AGENT);
        int guard = 0;
        while (__hip_atomic_load(&ctr[bA * 32], __ATOMIC_RELAXED, __HIP_MEMORY_SCOPE_AGENT) < 8u ||
               __hip_atomic_load(&ctr[bB * 32], __ATOMIC_RELAXED, __HIP_MEMORY_SCOPE_AGENT) < 8u) {
            if (++guard > 4000000) break;
            __builtin_amdgcn_s_sleep(1);
        }
    }
    __syncthreads();

    // ---- readout: batch A then batch B (s_hs reused) ----
#pragma unroll 1
    for (int pass = 0; pass < 2; ++pass) {
        const int bb = pass ? bB : bA;
        for (int idx = tid; idx < 16 * HH; idx += 512) {
            int tl = idx / HH, h = idx % HH;
            int t_g = sub * 16 + tl;
            s_hs[idx] = __hip_atomic_load(&hs[(t_g * BB + bb) * HH + h],
                                          __ATOMIC_RELAXED, __HIP_MEMORY_SCOPE_AGENT) - 2.0f;
        }
        __syncthreads();
        {
            int t_loc = tid >> 5;          // 0..15
            int o     = tid & 31;
            int t_g   = sub * 16 + t_loc;
            const float* hp = &s_hs[t_loc * HH];
            float acc = bh2o[o];
#pragma unroll 4
            for (int h = 0; h < 257; ++h) {          // mask_o zero for h>256
                float m = (h == 256) ? -1.f : 1.f;   // h==256: sign -1, exist 1 (zc=63)
                acc = fmaf(fmaxf(Wh2o[o * HH + h], 0.f) * m, hp[h], acc);
            }
            float sg = frcp(1.f + fexp2(-acc * L2E));
            out[(t_g * BB + bb) * OO + o] = sg;
        }
        __syncthreads();   // s_hs reads done before next pass restages
    }

    // Barrier B: all siblings finished READING biased hs -> safe to rewrite
    if (tid == 0) {
        __hip_atomic_fetch_add(&ctr[bA * 32], 1u, __ATOMIC_RELAXED, __HIP_MEMORY_SCOPE_AGENT);
        __hip_atomic_fetch_add(&ctr[bB * 32], 1u, __ATOMIC_RELAXED, __HIP_MEMORY_SCOPE_AGENT);
        int guard = 0;
        while (__hip_atomic_load(&ctr[bA * 32], __ATOMIC_RELAXED, __HIP_MEMORY_SCOPE_AGENT) < 16u ||
               __hip_atomic_load(&ctr[bB * 32], __ATOMIC_RELAXED, __HIP_MEMORY_SCOPE_AGENT) < 16u) {
            if (++guard > 4000000) break;
            __builtin_amdgcn_s_sleep(1);
        }
    }
    __syncthreads();

    // rewrite own rows of hs with TRUE values (word-granular agent stores)
    for (int idx = tid; idx < 40 * TT; idx += 512) {
        int row = idx >> 7;            // idx / 128
        int t   = idx & 127;
        __hip_atomic_store(&hs[(t * BB + bA) * HH + h0 + row], s_histA[row * HPAD + t],
                           __ATOMIC_RELAXED, __HIP_MEMORY_SCOPE_AGENT);
        __hip_atomic_store(&hs[(t * BB + bB) * HH + h0 + row], s_histB[row * HPAD + t],
                           __ATOMIC_RELAXED, __HIP_MEMORY_SCOPE_AGENT);
    }
}

extern "C" void kernel_launch(void* const* d_in, const int* in_sizes, int n_in,
                              void* d_out, int out_size, void* d_ws, size_t ws_size,
                              hipStream_t stream) {
    const float* x     = (const float*)d_in[0];
    const float* Rs    = (const float*)d_in[1];
    const float* Wx2h  = (const float*)d_in[2];
    const float* Wh2h  = (const float*)d_in[3];
    const float* bh2h  = (const float*)d_in[4];
    const float* Wh2o  = (const float*)d_in[5];
    const float* bh2o  = (const float*)d_in[6];
    const float* Wattn = (const float*)d_in[7];
    const float* battn = (const float*)d_in[8];
    const float* cplas = (const float*)d_in[9];
    float* out = (float*)d_out;
    float* hs  = out + TT * BB * OO;
    unsigned* ctr = (unsigned*)d_ws;   // 32 counters, 128B apart

    hipMemsetAsync(d_ws, 0, 32 * 32 * sizeof(unsigned), stream);
    hipLaunchKernelGGL(leaky_rnn_kernel, dim3(128), dim3(512), 0, stream,
                       x, Rs, Wx2h, Wh2h, bh2h, Wh2o, bh2o, Wattn, battn, cplas,
                       out, hs, ctr);
}

// Round 7
// 502.165 us; speedup vs baseline: 1.5302x; 1.5302x over previous
//
#include <hip/hip_runtime.h>

#define TT 128
#define BB 32
#define II 128
#define HH 320
#define OO 32
#define GG 8
#define HPAD 129   // s_hist row pitch (pad: rows are read down-column in final rewrite)

static __device__ __forceinline__ float fexp2(float x) { return __builtin_amdgcn_exp2f(x); }
static __device__ __forceinline__ float frcp(float x)  { return __builtin_amdgcn_rcpf(x); }

// tanh for x >= 0: 1 - 2/(e^{2x}+1), e^{2x} = exp2(x * 2*log2(e))
static __device__ __forceinline__ float tanh_pos(float x) {
    float e = fexp2(x * 2.8853900817779268f);
    return 1.0f - 2.0f * frcp(e + 1.0f);
}

__global__ __launch_bounds__(512, 2)
void leaky_rnn_kernel(const float* __restrict__ x, const float* __restrict__ Rs,
                      const float* __restrict__ Wx2h, const float* __restrict__ Wh2h,
                      const float* __restrict__ bh2h, const float* __restrict__ Wh2o,
                      const float* __restrict__ bh2o, const float* __restrict__ Wattn,
                      const float* __restrict__ battn, const float* __restrict__ cplas,
                      float* __restrict__ out, float* __restrict__ hs,
                      unsigned* __restrict__ ctr)
{
    const int tid  = threadIdx.x;
    const int bid  = blockIdx.x;
    const int b    = bid >> 3;     // batch  (round-0 proven mapping)
    const int sub  = bid & 7;      // 8 blocks per batch, 40 rows each
    const int w    = tid >> 6;     // wave 0..7
    const int lane = tid & 63;
    const int h0   = sub * 40;

    __shared__ float s_ea[GG * HH];      // masked relu(W_attn)
    __shared__ float s_out[2][HH];       // double-buffered prev-output (by t parity)
    __shared__ float s_logit[GG];
    __shared__ float s_hist[40 * HPAD];  // this block's 40 rows x 128 t (true values)
                                         // written by publisher lanes in-loop; READ
                                         // ONLY in the final phase (after barriers)
                                         // -> no in-loop LDS write->read race.
    __shared__ float s_hs[16 * HH];      // readout staging

    // ---- one-time init ----
    for (int idx = tid; idx < GG * HH; idx += 512) {
        int h = idx % HH;
        float m = (h < 256) ? 1.f : (h == 256 ? -1.f : 0.f);  // mask_a (zc=63!)
        s_ea[idx] = fmaxf(Wattn[idx], 0.f) * m;
    }
    if (tid < HH) { s_out[0][tid] = 0.f; s_out[1][tid] = 0.f; }  // output0 = relu(0)

    // plastic weights in registers: 5 rows/wave, lane owns cols {lane, lane+64,...}
    float wx[5][2], wh[5][5], st[5], bh[5];
    int hrow[5];
#pragma unroll
    for (int r = 0; r < 5; ++r) {
        int h = h0 + w * 5 + r;
        hrow[r] = h;
        bh[r] = bh2h[h];
        st[r] = 0.f;
#pragma unroll
        for (int c = 0; c < 2; ++c)
            wx[r][c] = fmaxf(Wx2h[h * II + lane + 64 * c], 0.f);   // wx0 = relu(W_x2h)
#pragma unroll
        for (int c = 0; c < 5; ++c) {
            int j = lane + 64 * c;
            float v = fmaxf(Wh2h[h * HH + j], 0.f);
            v = (c == 4) ? -v : v;            // sign_h: j>=256 -> -1
            wh[r][c] = (j == h) ? 0.f : v;    // zero diagonal (1-eye)
        }
    }
    float batt = battn[w];  // wave w handles attn group g = w
    float c0 = fabsf(cplas[0]), c1 = fabsf(cplas[1]), c2 = fabsf(cplas[2]);
    float c3 = fabsf(cplas[3]), c4 = fabsf(cplas[4]), c5 = fabsf(cplas[5]);

    const float AX  = (float)(0.02 / 0.1);   // 0.2
    const float AW  = (float)(0.02 / 0.2);   // 0.1
    const float OMX = 1.f - AX;
    const float OMW = 1.f - AW;
    const float L2E = 1.4426950408889634f;

    __syncthreads();

    // prefetch x (both halves, per-thread regs) and Rs for t=0
    float xv0n = x[b * II + lane];
    float xv1n = x[b * II + lane + 64];
    float Rvn  = Rs[b];

#pragma unroll 1
    for (int t = 0; t < TT; ++t) {
        const float* so_cur = s_out[t & 1];
        float*       so_nxt = s_out[(t + 1) & 1];
        float xv0 = xv0n, xv1 = xv1n;
        float A   = AW * Rvn;

        // ---- attention logits: g = w, reduce over H ----
        float lp = 0.f;
#pragma unroll
        for (int k = 0; k < 5; ++k) {
            int hh2 = lane + 64 * k;
            lp = fmaf(s_ea[w * HH + hh2], so_cur[hh2], lp);
        }
#pragma unroll
        for (int m = 1; m < 64; m <<= 1) lp += __shfl_xor(lp, m, 64);
        if (lane == 0) s_logit[w] = lp + batt;
        __syncthreads();                                   // B1: s_logit visible

        // ---- redundant per-thread softmax (no staging barrier) ----
        float lg[8];
#pragma unroll
        for (int g = 0; g < 8; ++g) lg[g] = s_logit[g];
        float mx = lg[0];
#pragma unroll
        for (int g = 1; g < 8; ++g) mx = fmaxf(mx, lg[g]);
        float se = 0.f, eg[8];
#pragma unroll
        for (int g = 0; g < 8; ++g) { eg[g] = fexp2((lg[g] - mx) * L2E); se += eg[g]; }
        float rinv = frcp(se);
        // same op order as round 2: ((xv*eg)*8)*rinv -> bit-identical
        float xmc0 = xv0 * eg[lane >> 4] * 8.f * rinv;
        float xmc1 = xv1 * eg[(lane >> 4) + 4] * 8.f * rinv;

        float oc[5];
#pragma unroll
        for (int c = 0; c < 5; ++c) oc[c] = so_cur[lane + 64 * c];

        // ---- 5 row-dot partials, ILP-interleaved butterfly ----
        float p[5];
#pragma unroll
        for (int r = 0; r < 5; ++r) {
            int h = hrow[r];
            float pp = fmaxf(wx[r][0], 0.f) * xmc0;
            pp = fmaf(fmaxf(wx[r][1], 0.f), xmc1, pp);
#pragma unroll
            for (int c = 0; c < 5; ++c) {
                float wv = fmaxf(wh[r][c], 0.f);
                float so = (c == 4) ? -oc[4] : oc[c];        // sign_h fold
                float term = wv * so;
                term = ((lane + 64 * c) == h) ? 0.f : term;  // exclude diagonal
                pp += term;
            }
            p[r] = pp;
        }
#pragma unroll
        for (int m = 1; m < 64; m <<= 1) {
#pragma unroll
            for (int r = 0; r < 5; ++r) p[r] += __shfl_xor(p[r], m, 64);
        }

        float no[5];
#pragma unroll
        for (int r = 0; r < 5; ++r) {
            float total = p[r] + bh[r];
            st[r] = fmaf(st[r], OMX, total * AX);
            no[r] = tanh_pos(fmaxf(st[r], 0.f));
        }

        // ---- batched publish: lanes 0..4 store 5 consecutive h (one line).
        //      Biased (+2): poison 0xAA.. and memset-0 are < 1. ----
        {
            float pub = no[0];
            pub = (lane == 1) ? no[1] : pub;
            pub = (lane == 2) ? no[2] : pub;
            pub = (lane == 3) ? no[3] : pub;
            pub = (lane == 4) ? no[4] : pub;
            if (lane < 5) {
                __hip_atomic_store(&hs[(t * BB + b) * HH + h0 + w * 5 + lane], pub + 2.0f,
                                   __ATOMIC_RELAXED, __HIP_MEMORY_SCOPE_AGENT);
                s_hist[(w * 5 + lane) * HPAD + t] = pub;   // true value for final rewrite
            }
        }

        // ---- plastic weight update (regs only; overlaps store propagation) ----
        if (t < TT - 1) {
            float Ac0 = A * c0, Ac1 = A * c1, Ac2 = A * c2;
            float Ac3 = A * c3, Ac4 = A * c4, Ac5 = A * c5;
#pragma unroll
            for (int r = 0; r < 5; ++r) {
                float u  = fmaf(Ac2, no[r], Ac0);
                float v  = Ac1 * no[r];
                float pp = fmaf(Ac5, no[r], Ac3);
                float qq = Ac4 * no[r];
                wx[r][0] = fmaf(wx[r][0], OMW, fmaf(u, xmc0, v));
                wx[r][1] = fmaf(wx[r][1], OMW, fmaf(u, xmc1, v));
#pragma unroll
                for (int c = 0; c < 5; ++c)
                    wh[r][c] = fmaf(wh[r][c], OMW, fmaf(pp, oc[c], qq));
            }
        }

        // prefetch next x/R while publish stores are in flight
        if (t + 1 < TT) {
            xv0n = x[((t + 1) * BB + b) * II + lane];
            xv1n = x[((t + 1) * BB + b) * II + lane + 64];
            Rvn  = Rs[(t + 1) * BB + b];
        }

        // ---- gather next-step output into the OTHER buffer (no WAR barrier).
        //      UNIFORM POLL of all 320 rows from hs -- own-block rows go
        //      through the same proven agent/LLC path (their stores were
        //      issued earliest -> visible first; critical path is the max
        //      over remote rows anyway). This removes the round-2 latent
        //      LDS write->read race entirely.
        //      PIPELINED 4-DEEP POLL: keep 4 independent flag loads in
        //      flight, check the oldest -> detection granularity ~ loop
        //      body instead of a full LLC RTT per probe. ----
        if (t < TT - 1 && tid < HH) {
            const float* p2 = &hs[(t * BB + b) * HH + tid];
            float va = __hip_atomic_load(p2, __ATOMIC_RELAXED, __HIP_MEMORY_SCOPE_AGENT);
            float vb = __hip_atomic_load(p2, __ATOMIC_RELAXED, __HIP_MEMORY_SCOPE_AGENT);
            float vc = __hip_atomic_load(p2, __ATOMIC_RELAXED, __HIP_MEMORY_SCOPE_AGENT);
            float vd = __hip_atomic_load(p2, __ATOMIC_RELAXED, __HIP_MEMORY_SCOPE_AGENT);
            int guard = 0;
            while (va < 1.0f && ++guard < 2000000) {   // failsafe: never hang
                va = vb; vb = vc; vc = vd;
                vd = __hip_atomic_load(p2, __ATOMIC_RELAXED, __HIP_MEMORY_SCOPE_AGENT);
            }
            so_nxt[tid] = va - 2.0f;
        }
        __syncthreads();                                   // B2: so_nxt sealed
    }

    // ======== final phase (proven round-0/2 structure, unchanged) ========
    // Barrier A among the 8 sibling blocks: everyone's t-loop done, all hs published.
    if (tid == 0) {
        __hip_atomic_fetch_add(&ctr[b * 32], 1u, __ATOMIC_RELAXED, __HIP_MEMORY_SCOPE_AGENT);
        int guard = 0;
        while (__hip_atomic_load(&ctr[b * 32], __ATOMIC_RELAXED, __HIP_MEMORY_SCOPE_AGENT) < 8u) {
            if (++guard > 2000000) break;
            __builtin_amdgcn_s_sleep(1);
        }
    }
    __syncthreads();

    // readout staging: load biased hs, subtract bias
    for (int idx = tid; idx < 16 * HH; idx += 512) {
        int tl = idx / HH, h = idx % HH;
        int t_g = sub * 16 + tl;
        s_hs[idx] = __hip_atomic_load(&hs[(t_g * BB + b) * HH + h],
                                      __ATOMIC_RELAXED, __HIP_MEMORY_SCOPE_AGENT) - 2.0f;
    }
    __syncthreads();
    {
        int t_loc = tid >> 5;          // 0..15
        int o     = tid & 31;
        int t_g   = sub * 16 + t_loc;
        const float* hp = &s_hs[t_loc * HH];
        float acc = bh2o[o];
#pragma unroll 4
        for (int h = 0; h < 257; ++h) {          // mask_o zero for h>256
            float m = (h == 256) ? -1.f : 1.f;   // h==256: sign -1, exist 1 (zc=63)
            acc = fmaf(fmaxf(Wh2o[o * HH + h], 0.f) * m, hp[h], acc);
        }
        float sg = frcp(1.f + fexp2(-acc * L2E));
        out[(t_g * BB + b) * OO + o] = sg;
    }

    // Barrier B: all siblings finished READING biased hs -> safe to rewrite
    __syncthreads();
    if (tid == 0) {
        __hip_atomic_fetch_add(&ctr[b * 32], 1u, __ATOMIC_RELAXED, __HIP_MEMORY_SCOPE_AGENT);
        int guard = 0;
        while (__hip_atomic_load(&ctr[b * 32], __ATOMIC_RELAXED, __HIP_MEMORY_SCOPE_AGENT) < 16u) {
            if (++guard > 2000000) break;
            __builtin_amdgcn_s_sleep(1);
        }
    }
    __syncthreads();

    // rewrite own rows of hs with TRUE values (word-granular agent stores)
    for (int idx = tid; idx < 40 * TT; idx += 512) {
        int row = idx >> 7;            // idx / 128
        int t   = idx & 127;
        __hip_atomic_store(&hs[(t * BB + b) * HH + h0 + row], s_hist[row * HPAD + t],
                           __ATOMIC_RELAXED, __HIP_MEMORY_SCOPE_AGENT);
    }
}

extern "C" void kernel_launch(void* const* d_in, const int* in_sizes, int n_in,
                              void* d_out, int out_size, void* d_ws, size_t ws_size,
                              hipStream_t stream) {
    const float* x     = (const float*)d_in[0];
    const float* Rs    = (const float*)d_in[1];
    const float* Wx2h  = (const float*)d_in[2];
    const float* Wh2h  = (const float*)d_in[3];
    const float* bh2h  = (const float*)d_in[4];
    const float* Wh2o  = (const float*)d_in[5];
    const float* bh2o  = (const float*)d_in[6];
    const float* Wattn = (const float*)d_in[7];
    const float* battn = (const float*)d_in[8];
    const float* cplas = (const float*)d_in[9];
    float* out = (float*)d_out;
    float* hs  = out + TT * BB * OO;
    unsigned* ctr = (unsigned*)d_ws;   // 32 counters, 128B apart

    hipMemsetAsync(d_ws, 0, 32 * 32 * sizeof(unsigned), stream);
    hipLaunchKernelGGL(leaky_rnn_kernel, dim3(256), dim3(512), 0, stream,
                       x, Rs, Wx2h, Wh2h, bh2h, Wh2o, bh2o, Wattn, battn, cplas,
                       out, hs, ctr);
}

// Round 8
// 438.264 us; speedup vs baseline: 1.7533x; 1.1458x over previous
//
#include <hip/hip_runtime.h>

#define TT 128
#define BB 32
#define II 128
#define HH 320
#define OO 32
#define GG 8
#define HPAD 129   // s_hist row pitch (pad: rows are read down-column in final rewrite)

static __device__ __forceinline__ float fexp2(float x) { return __builtin_amdgcn_exp2f(x); }
static __device__ __forceinline__ float frcp(float x)  { return __builtin_amdgcn_rcpf(x); }

// tanh for x >= 0: 1 - 2/(e^{2x}+1), e^{2x} = exp2(x * 2*log2(e))
static __device__ __forceinline__ float tanh_pos(float x) {
    float e = fexp2(x * 2.8853900817779268f);
    return 1.0f - 2.0f * frcp(e + 1.0f);
}

// ---- DPP wave-64 sum reduce (VALU pipe, ~10cy/level) ----
// row_shr:1/2/4/8 build per-16-row prefix sums (lane15/31/47/63 = row sums),
// row_bcast:15 + row_bcast:31 fold rows; lane 63 ends with the full sum.
template<int CTRL>
static __device__ __forceinline__ float dpp_add(float v) {
    int t = __builtin_amdgcn_update_dpp(0, __builtin_bit_cast(int, v),
                                        CTRL, 0xf, 0xf, true);
    return v + __builtin_bit_cast(float, t);
}
static __device__ __forceinline__ float bcast63(float v) {
    return __builtin_bit_cast(float,
        __builtin_amdgcn_readlane(__builtin_bit_cast(int, v), 63));
}
static __device__ __forceinline__ float wave_sum(float v) {
    v = dpp_add<0x111>(v);   // row_shr:1
    v = dpp_add<0x112>(v);   // row_shr:2
    v = dpp_add<0x114>(v);   // row_shr:4
    v = dpp_add<0x118>(v);   // row_shr:8
    v = dpp_add<0x142>(v);   // row_bcast:15
    v = dpp_add<0x143>(v);   // row_bcast:31
    return bcast63(v);
}

__global__ __launch_bounds__(512, 2)
void leaky_rnn_kernel(const float* __restrict__ x, const float* __restrict__ Rs,
                      const float* __restrict__ Wx2h, const float* __restrict__ Wh2h,
                      const float* __restrict__ bh2h, const float* __restrict__ Wh2o,
                      const float* __restrict__ bh2o, const float* __restrict__ Wattn,
                      const float* __restrict__ battn, const float* __restrict__ cplas,
                      float* __restrict__ out, float* __restrict__ hs,
                      unsigned* __restrict__ ctr)
{
    const int tid  = threadIdx.x;
    const int bid  = blockIdx.x;
    const int b    = bid >> 3;     // batch  (round-0 proven mapping)
    const int sub  = bid & 7;      // 8 blocks per batch, 40 rows each
    const int w    = tid >> 6;     // wave 0..7
    const int lane = tid & 63;
    const int h0   = sub * 40;

    __shared__ float s_ea[GG * HH];      // masked relu(W_attn)
    __shared__ float s_out[2][HH];       // double-buffered prev-output (by t parity)
    __shared__ float s_logit[GG];
    __shared__ float s_hist[40 * HPAD];  // this block's 40 rows x 128 t (true values)
                                         // in-loop: WRITTEN only (publisher lanes);
                                         // READ only in the final phase after barriers.
    __shared__ float s_hs[16 * HH];      // readout staging

    // ---- one-time init ----
    for (int idx = tid; idx < GG * HH; idx += 512) {
        int h = idx % HH;
        float m = (h < 256) ? 1.f : (h == 256 ? -1.f : 0.f);  // mask_a (zc=63!)
        s_ea[idx] = fmaxf(Wattn[idx], 0.f) * m;
    }
    if (tid < HH) { s_out[0][tid] = 0.f; s_out[1][tid] = 0.f; }  // output0 = relu(0)

    // plastic weights in registers: 5 rows/wave, lane owns cols {lane, lane+64,...}
    float wx[5][2], wh[5][5], st[5], bh[5];
    int hrow[5];
#pragma unroll
    for (int r = 0; r < 5; ++r) {
        int h = h0 + w * 5 + r;
        hrow[r] = h;
        bh[r] = bh2h[h];
        st[r] = 0.f;
#pragma unroll
        for (int c = 0; c < 2; ++c)
            wx[r][c] = fmaxf(Wx2h[h * II + lane + 64 * c], 0.f);   // wx0 = relu(W_x2h)
#pragma unroll
        for (int c = 0; c < 5; ++c) {
            int j = lane + 64 * c;
            float v = fmaxf(Wh2h[h * HH + j], 0.f);
            v = (c == 4) ? -v : v;            // sign_h: j>=256 -> -1
            wh[r][c] = (j == h) ? 0.f : v;    // zero diagonal (1-eye)
        }
    }
    float batt = battn[w];  // wave w handles attn group g = w
    float c0 = fabsf(cplas[0]), c1 = fabsf(cplas[1]), c2 = fabsf(cplas[2]);
    float c3 = fabsf(cplas[3]), c4 = fabsf(cplas[4]), c5 = fabsf(cplas[5]);

    const float AX  = (float)(0.02 / 0.1);   // 0.2
    const float AW  = (float)(0.02 / 0.2);   // 0.1
    const float OMX = 1.f - AX;
    const float OMW = 1.f - AW;
    const float L2E = 1.4426950408889634f;

    __syncthreads();

    // prefetch x (both halves, per-thread regs) and Rs for t=0
    float xv0n = x[b * II + lane];
    float xv1n = x[b * II + lane + 64];
    float Rvn  = Rs[b];

#pragma unroll 1
    for (int t = 0; t < TT; ++t) {
        const float* so_cur = s_out[t & 1];
        float*       so_nxt = s_out[(t + 1) & 1];
        float xv0 = xv0n, xv1 = xv1n;
        float A   = AW * Rvn;

        // ---- attention logits: g = w, reduce over H (DPP, VALU pipe) ----
        float lp = 0.f;
#pragma unroll
        for (int k = 0; k < 5; ++k) {
            int hh2 = lane + 64 * k;
            lp = fmaf(s_ea[w * HH + hh2], so_cur[hh2], lp);
        }
        float lt = wave_sum(lp);
        if (lane == 0) s_logit[w] = lt + batt;
        __syncthreads();                                   // B1: s_logit visible

        // ---- redundant per-thread softmax (no staging barrier) ----
        float lg[8];
#pragma unroll
        for (int g = 0; g < 8; ++g) lg[g] = s_logit[g];
        float mx = lg[0];
#pragma unroll
        for (int g = 1; g < 8; ++g) mx = fmaxf(mx, lg[g]);
        float se = 0.f, eg[8];
#pragma unroll
        for (int g = 0; g < 8; ++g) { eg[g] = fexp2((lg[g] - mx) * L2E); se += eg[g]; }
        float rinv = frcp(se);
        float xmc0 = xv0 * eg[lane >> 4] * 8.f * rinv;
        float xmc1 = xv1 * eg[(lane >> 4) + 4] * 8.f * rinv;

        float oc[5];
#pragma unroll
        for (int c = 0; c < 5; ++c) oc[c] = so_cur[lane + 64 * c];

        // ---- 5 row-dot partials, 5-way ILP DPP reduce ----
        float p[5];
#pragma unroll
        for (int r = 0; r < 5; ++r) {
            int h = hrow[r];
            float pp = fmaxf(wx[r][0], 0.f) * xmc0;
            pp = fmaf(fmaxf(wx[r][1], 0.f), xmc1, pp);
#pragma unroll
            for (int c = 0; c < 5; ++c) {
                float wv = fmaxf(wh[r][c], 0.f);
                float so = (c == 4) ? -oc[4] : oc[c];        // sign_h fold
                float term = wv * so;
                term = ((lane + 64 * c) == h) ? 0.f : term;  // exclude diagonal
                pp += term;
            }
            p[r] = pp;
        }
#define DPP_LEVEL(CTRL) \
        p[0] = dpp_add<CTRL>(p[0]); p[1] = dpp_add<CTRL>(p[1]); \
        p[2] = dpp_add<CTRL>(p[2]); p[3] = dpp_add<CTRL>(p[3]); \
        p[4] = dpp_add<CTRL>(p[4]);
        DPP_LEVEL(0x111)   // row_shr:1
        DPP_LEVEL(0x112)   // row_shr:2
        DPP_LEVEL(0x114)   // row_shr:4
        DPP_LEVEL(0x118)   // row_shr:8
        DPP_LEVEL(0x142)   // row_bcast:15
        DPP_LEVEL(0x143)   // row_bcast:31
#undef DPP_LEVEL

        float no[5];
#pragma unroll
        for (int r = 0; r < 5; ++r) {
            float total = bcast63(p[r]) + bh[r];
            st[r] = fmaf(st[r], OMX, total * AX);
            no[r] = tanh_pos(fmaxf(st[r], 0.f));
        }

        // ---- batched publish: lanes 0..4 store 5 consecutive h (one line).
        //      Biased (+2): poison 0xAA.. and memset-0 are < 1.
        //      Publisher ALSO writes its true value into so_nxt (LDS):
        //      race-free own-row fast path -- the B2 barrier below orders
        //      this write against all next-step readers (this is the
        //      ordering the round-2 s_hist fast path lacked). ----
        {
            float pub = no[0];
            pub = (lane == 1) ? no[1] : pub;
            pub = (lane == 2) ? no[2] : pub;
            pub = (lane == 3) ? no[3] : pub;
            pub = (lane == 4) ? no[4] : pub;
            if (lane < 5) {
                __hip_atomic_store(&hs[(t * BB + b) * HH + h0 + w * 5 + lane], pub + 2.0f,
                                   __ATOMIC_RELAXED, __HIP_MEMORY_SCOPE_AGENT);
                s_hist[(w * 5 + lane) * HPAD + t] = pub;   // true value for final rewrite
                so_nxt[h0 + w * 5 + lane] = pub;           // own-row fast path (B2-ordered)
            }
        }

        // ---- plastic weight update (regs only; overlaps store propagation) ----
        if (t < TT - 1) {
            float Ac0 = A * c0, Ac1 = A * c1, Ac2 = A * c2;
            float Ac3 = A * c3, Ac4 = A * c4, Ac5 = A * c5;
#pragma unroll
            for (int r = 0; r < 5; ++r) {
                float u  = fmaf(Ac2, no[r], Ac0);
                float v  = Ac1 * no[r];
                float pp = fmaf(Ac5, no[r], Ac3);
                float qq = Ac4 * no[r];
                wx[r][0] = fmaf(wx[r][0], OMW, fmaf(u, xmc0, v));
                wx[r][1] = fmaf(wx[r][1], OMW, fmaf(u, xmc1, v));
#pragma unroll
                for (int c = 0; c < 5; ++c)
                    wh[r][c] = fmaf(wh[r][c], OMW, fmaf(pp, oc[c], qq));
            }
        }

        // prefetch next x/R while publish stores are in flight
        if (t + 1 < TT) {
            xv0n = x[((t + 1) * BB + b) * II + lane];
            xv1n = x[((t + 1) * BB + b) * II + lane + 64];
            Rvn  = Rs[(t + 1) * BB + b];
        }

        // ---- gather the 280 REMOTE rows into the other buffer (own 40 rows
        //      were written to so_nxt by the publishers above; B2 orders).
        //      4-deep pipelined poll (proven R7). ----
        if (t < TT - 1 && tid < HH && !(tid >= h0 && tid < h0 + 40)) {
            const float* p2 = &hs[(t * BB + b) * HH + tid];
            float va = __hip_atomic_load(p2, __ATOMIC_RELAXED, __HIP_MEMORY_SCOPE_AGENT);
            float vb = __hip_atomic_load(p2, __ATOMIC_RELAXED, __HIP_MEMORY_SCOPE_AGENT);
            float vc = __hip_atomic_load(p2, __ATOMIC_RELAXED, __HIP_MEMORY_SCOPE_AGENT);
            float vd = __hip_atomic_load(p2, __ATOMIC_RELAXED, __HIP_MEMORY_SCOPE_AGENT);
            int guard = 0;
            while (va < 1.0f && ++guard < 2000000) {   // failsafe: never hang
                va = vb; vb = vc; vc = vd;
                vd = __hip_atomic_load(p2, __ATOMIC_RELAXED, __HIP_MEMORY_SCOPE_AGENT);
            }
            so_nxt[tid] = va - 2.0f;
        }
        __syncthreads();                                   // B2: so_nxt sealed
    }

    // ======== final phase (proven structure, unchanged) ========
    // Barrier A among the 8 sibling blocks: everyone's t-loop done, all hs published.
    if (tid == 0) {
        __hip_atomic_fetch_add(&ctr[b * 32], 1u, __ATOMIC_RELAXED, __HIP_MEMORY_SCOPE_AGENT);
        int guard = 0;
        while (__hip_atomic_load(&ctr[b * 32], __ATOMIC_RELAXED, __HIP_MEMORY_SCOPE_AGENT) < 8u) {
            if (++guard > 2000000) break;
            __builtin_amdgcn_s_sleep(1);
        }
    }
    __syncthreads();

    // readout staging: load biased hs, subtract bias
    for (int idx = tid; idx < 16 * HH; idx += 512) {
        int tl = idx / HH, h = idx % HH;
        int t_g = sub * 16 + tl;
        s_hs[idx] = __hip_atomic_load(&hs[(t_g * BB + b) * HH + h],
                                      __ATOMIC_RELAXED, __HIP_MEMORY_SCOPE_AGENT) - 2.0f;
    }
    __syncthreads();
    {
        int t_loc = tid >> 5;          // 0..15
        int o     = tid & 31;
        int t_g   = sub * 16 + t_loc;
        const float* hp = &s_hs[t_loc * HH];
        float acc = bh2o[o];
#pragma unroll 4
        for (int h = 0; h < 257; ++h) {          // mask_o zero for h>256
            float m = (h == 256) ? -1.f : 1.f;   // h==256: sign -1, exist 1 (zc=63)
            acc = fmaf(fmaxf(Wh2o[o * HH + h], 0.f) * m, hp[h], acc);
        }
        float sg = frcp(1.f + fexp2(-acc * L2E));
        out[(t_g * BB + b) * OO + o] = sg;
    }

    // Barrier B: all siblings finished READING biased hs -> safe to rewrite
    __syncthreads();
    if (tid == 0) {
        __hip_atomic_fetch_add(&ctr[b * 32], 1u, __ATOMIC_RELAXED, __HIP_MEMORY_SCOPE_AGENT);
        int guard = 0;
        while (__hip_atomic_load(&ctr[b * 32], __ATOMIC_RELAXED, __HIP_MEMORY_SCOPE_AGENT) < 16u) {
            if (++guard > 2000000) break;
            __builtin_amdgcn_s_sleep(1);
        }
    }
    __syncthreads();

    // rewrite own rows of hs with TRUE values (word-granular agent stores)
    for (int idx = tid; idx < 40 * TT; idx += 512) {
        int row = idx >> 7;            // idx / 128
        int t   = idx & 127;
        __hip_atomic_store(&hs[(t * BB + b) * HH + h0 + row], s_hist[row * HPAD + t],
                           __ATOMIC_RELAXED, __HIP_MEMORY_SCOPE_AGENT);
    }
}

extern "C" void kernel_launch(void* const* d_in, const int* in_sizes, int n_in,
                              void* d_out, int out_size, void* d_ws, size_t ws_size,
                              hipStream_t stream) {
    const float* x     = (const float*)d_in[0];
    const float* Rs    = (const float*)d_in[1];
    const float* Wx2h  = (const float*)d_in[2];
    const float* Wh2h  = (const float*)d_in[3];
    const float* bh2h  = (const float*)d_in[4];
    const float* Wh2o  = (const float*)d_in[5];
    const float* bh2o  = (const float*)d_in[6];
    const float* Wattn = (const float*)d_in[7];
    const float* battn = (const float*)d_in[8];
    const float* cplas = (const float*)d_in[9];
    float* out = (float*)d_out;
    float* hs  = out + TT * BB * OO;
    unsigned* ctr = (unsigned*)d_ws;   // 32 counters, 128B apart

    hipMemsetAsync(d_ws, 0, 32 * 32 * sizeof(unsigned), stream);
    hipLaunchKernelGGL(leaky_rnn_kernel, dim3(256), dim3(512), 0, stream,
                       x, Rs, Wx2h, Wh2h, bh2h, Wh2o, bh2o, Wattn, battn, cplas,
                       out, hs, ctr);
}